// Round 5
// baseline (96.694 us; speedup 1.0000x reference)
//
#include <hip/hip_runtime.h>
#include <cstdint>

#define NROWS 8192
#define DDIM  256
#define THR   0.95f
#define EPSN  1e-8f
#define IMAX  0x7FFFFFFF
#define NCAT  80
#define MAXC  256   // max rows per category supported (actual ~102 +/- 10)

typedef unsigned short u16;
typedef short v8s __attribute__((ext_vector_type(8)));
typedef float v4f __attribute__((ext_vector_type(4)));

__device__ __forceinline__ u16 f2b(float f) {
    union { float f; unsigned int i; } v; v.f = f;
    if ((v.i & 0x7F800000u) == 0x7F800000u) {
        return (u16)((v.i >> 16) | ((v.i & 0xFFFFu) ? 0x40 : 0));
    }
    unsigned int r = v.i + 0x7FFFu + ((v.i >> 16) & 1u);
    return (u16)(r >> 16);
}

// ---- D1: row-normalize (fp32 norm, clamp eps) -> bf16 anorm. 1 row/wave. ----
__global__ __launch_bounds__(256) void k_norm(const float* __restrict__ kin,
                                              u16* __restrict__ anorm) {
    const int t = threadIdx.x, w = t >> 6, l = t & 63;
    const int row = (blockIdx.x << 2) + w;
    const float4 v = ((const float4*)(kin + (size_t)row * DDIM))[l];
    float s = v.x * v.x + v.y * v.y + v.z * v.z + v.w * v.w;
    for (int o = 32; o >= 1; o >>= 1) s += __shfl_xor(s, o);
    const float rn = 1.0f / fmaxf(sqrtf(s), EPSN);
    ushort4 o4;
    o4.x = f2b(v.x * rn); o4.y = f2b(v.y * rn);
    o4.z = f2b(v.z * rn); o4.w = f2b(v.w * rn);
    ((ushort4*)(anorm + (size_t)row * DDIM))[l] = o4;
}

// ---- D2: one block per category. Build row list, MFMA hit search, all outputs. ----
__global__ __launch_bounds__(256) void k_cat(const u16* __restrict__ anorm,
                                             const float* __restrict__ kin,
                                             const int* __restrict__ cat,
                                             const float* __restrict__ sc,
                                             float* __restrict__ out) {
    const int c = blockIdx.x;
    const int t = threadIdx.x;
    const int wv = t >> 6, l = t & 63;
    const int lo16 = l & 15, quad = l >> 4;

    __shared__ int lst[MAXC];        // ascending original row indices of this category
    __shared__ int colH1[MAXC];      // per local column: min local row p<q with sim>=THR
    __shared__ int psum[256];
    __shared__ int mlist[MAXC];
    __shared__ int mcnt_s, nc_s;

    // --- stable list build: thread t owns rows [32t, 32t+32) ---
    {
        const int r0 = t << 5;
        int cnt = 0;
        for (int k = 0; k < 32; ++k) cnt += (cat[r0 + k] == c);
        psum[t] = cnt;
        __syncthreads();
        for (int off = 1; off < 256; off <<= 1) {           // inclusive scan
            const int v = (t >= off) ? psum[t - off] : 0;
            __syncthreads();
            psum[t] += v;
            __syncthreads();
        }
        int pos = psum[t] - cnt;
        if (t == 255) { nc_s = psum[255] < MAXC ? psum[255] : MAXC; mcnt_s = 0; }
        for (int k = 0; k < 32; ++k) {
            const int r = r0 + k;
            if (cat[r] == c) { if (pos < MAXC) lst[pos] = r; ++pos; }
        }
    }
    colH1[t] = IMAX;
    __syncthreads();
    const int nc = nc_s;
    const int ncT = (nc + 15) >> 4;

    // --- MFMA hit search: wave wv owns col-tiles ct = wv, wv+4, ... ---
    for (int ct = wv; ct < ncT; ct += 4) {
        const int qloc = (ct << 4) + lo16;
        const int gq = lst[qloc < nc ? qloc : nc - 1];
        const u16* qrow = anorm + ((size_t)gq << 8) + (quad << 3);
        v8s bfr[8];
#pragma unroll
        for (int kk = 0; kk < 8; ++kk) bfr[kk] = *(const v8s*)(qrow + (kk << 5));

        for (int rt = 0; rt <= ct; ++rt) {
            const int ploc = (rt << 4) + lo16;
            const int gp = lst[ploc < nc ? ploc : nc - 1];
            const u16* prow = anorm + ((size_t)gp << 8) + (quad << 3);
            v4f acc = {0.f, 0.f, 0.f, 0.f};
#pragma unroll
            for (int kk = 0; kk < 8; ++kk) {
                const v8s af = *(const v8s*)(prow + (kk << 5));
                acc = __builtin_amdgcn_mfma_f32_16x16x32_bf16(af, bfr[kk], acc, 0, 0, 0);
            }
            // D layout: col n = lane&15 (-> qloc), row m = quad*4 + reg (-> p)
#pragma unroll
            for (int reg = 0; reg < 4; ++reg) {
                const int p = (rt << 4) + (quad << 2) + reg;
                if (acc[reg] >= THR && p < qloc && qloc < nc) atomicMin(&colH1[lo16 + (ct << 4)], p);
            }
        }
    }
    __syncthreads();

    // --- block-local merge list (columns whose first hit is off-diagonal) ---
    if (t < nc && colH1[t] != IMAX) mlist[atomicAdd(&mcnt_s, 1)] = t;
    __syncthreads();
    const int mc = mcnt_s;

    // --- scalar outputs ---
    float* cats  = out + (size_t)NROWS * DDIM;
    float* scso  = cats + NROWS;
    float* keepo = scso + NROWS;
    if (t < nc) {
        const int g = lst[t];
        const bool keep = (colH1[t] == IMAX);
        cats[g]  = keep ? (float)c : -1.0f;
        scso[g]  = keep ? sc[g] : 0.0f;
        keepo[g] = keep ? 1.0f : 0.0f;
    }

    // --- fused rows: 1 local row per wave iteration ---
    for (int i = wv; i < nc; i += 4) {
        const int g = lst[i];
        float4 o4 = {0.f, 0.f, 0.f, 0.f};
        if (colH1[i] == IMAX) {                      // kept: diagonal is sole first hit
            const float4 v = ((const float4*)(kin + ((size_t)g << 8)))[l];
            float ax = v.x, ay = v.y, az = v.z, aw = v.w;
            int cnt = 1;
            for (int k = 0; k < mc; ++k) {
                const int q = mlist[k];
                if (colH1[q] == i) {
                    const float4 b = ((const float4*)(kin + ((size_t)lst[q] << 8)))[l];
                    ax += b.x; ay += b.y; az += b.z; aw += b.w; ++cnt;
                }
            }
            const float fc = (float)cnt;
            o4.x = ax / fc; o4.y = ay / fc; o4.z = az / fc; o4.w = aw / fc;
        }
        ((float4*)(out + ((size_t)g << 8)))[l] = o4;
    }
}

extern "C" void kernel_launch(void* const* d_in, const int* in_sizes, int n_in,
                              void* d_out, int out_size, void* d_ws, size_t ws_size,
                              hipStream_t stream) {
    (void)in_sizes; (void)n_in; (void)out_size; (void)ws_size;
    const float* kin = (const float*)d_in[0];   // kernels fp32 [N*D]
    const int*   cat = (const int*)d_in[1];     // categories int32 [N]
    const float* sc  = (const float*)d_in[2];   // scores fp32 [N]
    float* out = (float*)d_out;                 // fp32 concat: fused|cats|scores|keep

    u16* anorm = (u16*)d_ws;                    // 4 MB bf16 normalized rows

    k_norm<<<NROWS / 4, 256, 0, stream>>>(kin, anorm);
    k_cat<<<NCAT, 256, 0, stream>>>(anorm, kin, cat, sc, out);
}